// Round 3
// baseline (451.111 us; speedup 1.0000x reference)
//
#include <hip/hip_runtime.h>
#include <hip/hip_bf16.h>
#include <cstdint>
#include <cmath>

#define SQL 2048
#define SKVL 2048
#define DD 128
#define NB 16
#define QBLK 64
#define KVB 64

typedef __attribute__((ext_vector_type(8))) short short8;
typedef __attribute__((ext_vector_type(4))) short short4v;
typedef __attribute__((ext_vector_type(4))) float f32x4;

__device__ __forceinline__ ushort f2bf(float x) {
    union { float f; uint32_t u; } v; v.f = x;
    uint32_t r = v.u + 0x7FFFu + ((v.u >> 16) & 1u);
    return (ushort)(r >> 16);
}

// fp32 -> bf16 with optional scale folded in; 8 elements/thread, exact grid.
__global__ void convert_scale_k(const float* __restrict__ in, ushort* __restrict__ out, float scale) {
    size_t i = (size_t)blockIdx.x * blockDim.x + threadIdx.x;
    const f32x4* p = (const f32x4*)in + i * 2;
    f32x4 a = p[0], b = p[1];
    short8 o;
    o[0] = (short)f2bf(a[0] * scale);
    o[1] = (short)f2bf(a[1] * scale);
    o[2] = (short)f2bf(a[2] * scale);
    o[3] = (short)f2bf(a[3] * scale);
    o[4] = (short)f2bf(b[0] * scale);
    o[5] = (short)f2bf(b[1] * scale);
    o[6] = (short)f2bf(b[2] * scale);
    o[7] = (short)f2bf(b[3] * scale);
    *((short8*)out + i) = o;
}

// V [B][SKV][D] fp32 -> V^T [B][D][SKV] bf16, 64x64 LDS tiles (+1 pad col).
__global__ void transpose_v(const float* __restrict__ v, ushort* __restrict__ vt) {
    __shared__ float tile[64][65];
    int bid = blockIdx.x;
    int dt = bid & 1;           // D/64 = 2
    int kt = (bid >> 1) & 31;   // SKV/64 = 32
    int b  = bid >> 6;
    int tx = threadIdx.x & 63, ty = threadIdx.x >> 6;  // 64 x 4
    const float* src = v + ((size_t)b * SKVL + (size_t)kt * 64) * DD + dt * 64;
#pragma unroll
    for (int r = ty; r < 64; r += 4)
        tile[r][tx] = src[(size_t)r * DD + tx];
    __syncthreads();
    ushort* dst = vt + ((size_t)b * DD + (size_t)dt * 64) * SKVL + (size_t)kt * 64;
#pragma unroll
    for (int r = ty; r < 64; r += 4)
        dst[(size_t)r * SKVL + tx] = f2bf(tile[tx][r]);
}

// Flash attention fwd. Grid = B * SQ/QBLK = 512 blocks, 256 thr (4 waves).
// Each wave owns 16 q-rows. Swapped QK^T: S^T = mfma(K, Q) so lane l holds
// scores for q = (l&15), kv = (l>>4)*4 + r per 16-kv subtile -> softmax
// reduce is 2 shfl_xor (16,32). PV as O^T = mfma(V^T, P^T): P stays
// lane-local (slot map kv = 16t + 4g + r consistent between V^T-frag load
// and P pack). Output O^T lane layout: q = l&15, d = dt*16 + (l>>4)*4 + r.
__global__ __launch_bounds__(256, 2) void fattn(
    const ushort* __restrict__ qb, const ushort* __restrict__ kb,
    const ushort* __restrict__ vtb, float* __restrict__ out)
{
    int bid = blockIdx.x;
    // XCD-bijective swizzle: 512 blocks over 8 XCDs, 64 contiguous per XCD
    // -> each XCD touches 2 batches' K/V (1 MB bf16 each) for L2 locality.
    int swz = (bid & 7) * 64 + (bid >> 3);
    int b  = swz >> 5;          // 32 q-tiles per batch
    int qt = swz & 31;
    int lane = threadIdx.x & 63;
    int w = threadIdx.x >> 6;
    int g = lane >> 4;
    int qi = lane & 15;
    int qrow = qt * QBLK + w * 16 + qi;

    // Q fragments: B-operand of S^T mfma. lane holds q = qi, d-slots = ks*32 + g*8 + j.
    const ushort* qptr = qb + ((size_t)b * SQL + qrow) * DD;
    short8 qf[4];
#pragma unroll
    for (int ks = 0; ks < 4; ++ks)
        qf[ks] = *(const short8*)(qptr + ks * 32 + g * 8);

    f32x4 acc[8];
#pragma unroll
    for (int i = 0; i < 8; ++i) acc[i] = (f32x4)0.f;
    float m = -1e30f, lsum = 0.f;

    const ushort* kbase = kb + (size_t)b * SKVL * DD;
    const ushort* vbase = vtb + (size_t)b * DD * SKVL;

    for (int kv0 = 0; kv0 < SKVL; kv0 += KVB) {
        // ---- QK^T: 4 kv-subtiles of 16, K dim = 128 = 4 x 32 ----
        f32x4 st[4];
#pragma unroll
        for (int sub = 0; sub < 4; ++sub) {
            const ushort* kptr = kbase + (size_t)(kv0 + sub * 16 + qi) * DD + g * 8;
            f32x4 s = (f32x4)0.f;
#pragma unroll
            for (int ks = 0; ks < 4; ++ks) {
                short8 kf = *(const short8*)(kptr + ks * 32);
                s = __builtin_amdgcn_mfma_f32_16x16x32_bf16(kf, qf[ks], s, 0, 0, 0);
            }
            st[sub] = s;
        }
        // ---- online softmax (scores already scaled by 1/sqrt(D)*log2e) ----
        float tmax = st[0][0];
#pragma unroll
        for (int s = 0; s < 4; ++s)
#pragma unroll
            for (int r = 0; r < 4; ++r) tmax = fmaxf(tmax, st[s][r]);
        tmax = fmaxf(tmax, __shfl_xor(tmax, 16));
        tmax = fmaxf(tmax, __shfl_xor(tmax, 32));
        float mnew = fmaxf(m, tmax);
        float alpha = exp2f(m - mnew);
        m = mnew;
        float psum = 0.f;
        short8 pb0, pb1;
#pragma unroll
        for (int s = 0; s < 4; ++s)
#pragma unroll
            for (int r = 0; r < 4; ++r) {
                float p = exp2f(st[s][r] - m);
                psum += p;
                ushort pv = f2bf(p);
                if (s < 2) pb0[s * 4 + r] = (short)pv;
                else       pb1[(s - 2) * 4 + r] = (short)pv;
            }
        lsum = lsum * alpha + psum;
#pragma unroll
        for (int i = 0; i < 8; ++i) {
            acc[i][0] *= alpha; acc[i][1] *= alpha;
            acc[i][2] *= alpha; acc[i][3] *= alpha;
        }
        // ---- PV: O^T += V^T * P^T, 8 d-tiles x 2 kv-halves ----
#pragma unroll
        for (int dt = 0; dt < 8; ++dt) {
            const ushort* vptr = vbase + (size_t)(dt * 16 + qi) * SKVL + kv0 + g * 4;
#pragma unroll
            for (int h = 0; h < 2; ++h) {
                short4v va = *(const short4v*)(vptr + h * 32);
                short4v vb = *(const short4v*)(vptr + h * 32 + 16);
                short8 vf;
                vf[0] = va[0]; vf[1] = va[1]; vf[2] = va[2]; vf[3] = va[3];
                vf[4] = vb[0]; vf[5] = vb[1]; vf[6] = vb[2]; vf[7] = vb[3];
                acc[dt] = __builtin_amdgcn_mfma_f32_16x16x32_bf16(vf, h ? pb1 : pb0, acc[dt], 0, 0, 0);
            }
        }
    }
    lsum += __shfl_xor(lsum, 16);
    lsum += __shfl_xor(lsum, 32);
    float inv = 1.f / lsum;
    float* optr = out + ((size_t)b * SQL + qrow) * DD + g * 4;
#pragma unroll
    for (int dt = 0; dt < 8; ++dt) {
        f32x4 o;
        o[0] = acc[dt][0] * inv; o[1] = acc[dt][1] * inv;
        o[2] = acc[dt][2] * inv; o[3] = acc[dt][3] * inv;
        *(f32x4*)(optr + dt * 16) = o;
    }
}

extern "C" void kernel_launch(void* const* d_in, const int* in_sizes, int n_in,
                              void* d_out, int out_size, void* d_ws, size_t ws_size,
                              hipStream_t stream) {
    const float* q = (const float*)d_in[0];
    const float* k = (const float*)d_in[1];
    const float* v = (const float*)d_in[2];
    float* out = (float*)d_out;

    uint8_t* w = (uint8_t*)d_ws;
    size_t tsz = (size_t)NB * SQL * DD * sizeof(ushort);  // 8 MB per tensor
    ushort* qb = (ushort*)w;
    ushort* kb = (ushort*)(w + tsz);
    ushort* vt = (ushort*)(w + 2 * tsz);

    // fold softmax scale and log2(e) into Q so the kernel uses exp2 directly
    float qscale = 1.4426950408889634f / sqrtf((float)DD);
    int n8 = NB * SQL * DD / 8;  // 524288 threads, exact
    convert_scale_k<<<n8 / 256, 256, 0, stream>>>(q, qb, qscale);
    convert_scale_k<<<n8 / 256, 256, 0, stream>>>(k, kb, 1.0f);
    transpose_v<<<NB * (SKVL / 64) * (DD / 64), 256, 0, stream>>>(v, vt);
    fattn<<<NB * (SQL / QBLK), 256, 0, stream>>>(qb, kb, vt, out);
}

// Round 4
// 165.680 us; speedup vs baseline: 2.7228x; 2.7228x over previous
//
#include <hip/hip_runtime.h>
#include <hip/hip_bf16.h>
#include <cstdint>
#include <cmath>

#define SQL 2048
#define SKVL 2048
#define DD 128
#define NB 16
#define QBLK 64
#define KVB 64
#define NT (SKVL / KVB)

typedef __attribute__((ext_vector_type(8))) short short8;
typedef __attribute__((ext_vector_type(4))) float f32x4;

__device__ __forceinline__ ushort f2bf(float x) {
    union { float f; uint32_t u; } v; v.f = x;
    uint32_t r = v.u + 0x7FFFu + ((v.u >> 16) & 1u);
    return (ushort)(r >> 16);
}

// fp32 -> bf16 with scale folded in; 8 elements/thread. (Used for Q.)
__global__ void convert_scale_k(const float* __restrict__ in, ushort* __restrict__ out, float scale) {
    size_t i = (size_t)blockIdx.x * blockDim.x + threadIdx.x;
    const f32x4* p = (const f32x4*)in + i * 2;
    f32x4 a = p[0], b = p[1];
    short8 o;
    o[0] = (short)f2bf(a[0] * scale);
    o[1] = (short)f2bf(a[1] * scale);
    o[2] = (short)f2bf(a[2] * scale);
    o[3] = (short)f2bf(a[3] * scale);
    o[4] = (short)f2bf(b[0] * scale);
    o[5] = (short)f2bf(b[1] * scale);
    o[6] = (short)f2bf(b[2] * scale);
    o[7] = (short)f2bf(b[3] * scale);
    *((short8*)out + i) = o;
}

// K fp32 [B][SKV][128] -> tiled swizzled bf16 [B][SKV/64][64 rows x 128 cols].
// Within a 16KB tile: elem (r,c) -> elem index r*128 + ((c>>3)^(r&7))*8 + (c&7).
// This IS the LDS image: global_load_lds copies it linearly; ds_read_b128 at
// chunk ((ks*4+g)^(r&7)) is bank-uniform (8 lanes per 16B slot = minimum).
__global__ void convert_k_tiled(const float* __restrict__ in, ushort* __restrict__ out) {
    int gid = blockIdx.x * blockDim.x + threadIdx.x;   // one 16B out-chunk (8 elems)
    int c16 = gid & 15;
    int rg  = gid >> 4;            // b*SKV + kv
    int r   = rg & 63;
    int tile = rg >> 6;            // b*32 + kt
    const f32x4* p = (const f32x4*)(in + (size_t)rg * DD + c16 * 8);
    f32x4 a = p[0], b = p[1];
    short8 o;
    o[0] = (short)f2bf(a[0]); o[1] = (short)f2bf(a[1]);
    o[2] = (short)f2bf(a[2]); o[3] = (short)f2bf(a[3]);
    o[4] = (short)f2bf(b[0]); o[5] = (short)f2bf(b[1]);
    o[6] = (short)f2bf(b[2]); o[7] = (short)f2bf(b[3]);
    int cs = c16 ^ (r & 7);
    *(short8*)(out + ((size_t)tile << 13) + r * 128 + cs * 8) = o;
}

// V fp32 [B][SKV][128] -> V^T tiled bf16 [B][SKV/64][128 d-rows x 64 kv],
// kv-columns PERMUTED to match the PV mfma slot map (so the fattn read is one
// b128) and XOR-swizzled: storage chunk cs' of row d holds logical chunk
// cs = cs'^(d&7); logical chunk cs=(h*4+g) elem j -> kv = h*32+g*4+(j&3)+16*(j>>2).
__global__ void convert_vt_tiled(const float* __restrict__ v, ushort* __restrict__ vt) {
    __shared__ float tile[64][129];
    int bid = blockIdx.x;          // b*32 + kt
    int kt = bid & 31;
    int b  = bid >> 5;
    int tx = threadIdx.x & 63, ty = threadIdx.x >> 6;  // 64 x 4
    const float* src = v + ((size_t)b * SKVL + (size_t)kt * 64) * DD;
#pragma unroll
    for (int r = ty; r < 64; r += 4) {
        tile[r][tx * 2]     = src[(size_t)r * DD + tx * 2];
        tile[r][tx * 2 + 1] = src[(size_t)r * DD + tx * 2 + 1];
    }
    __syncthreads();
    ushort* dst = vt + ((size_t)bid << 13);
#pragma unroll
    for (int i = 0; i < 4; ++i) {
        int q = threadIdx.x + 256 * i;   // 1024 chunks: d(128) x cs'(8)
        int d = q >> 3;
        int csp = q & 7;
        int cs = csp ^ (d & 7);
        int h = cs >> 2, g = cs & 3;
        short8 o;
#pragma unroll
        for (int j = 0; j < 8; ++j) {
            int kv = h * 32 + g * 4 + (j & 3) + 16 * (j >> 2);
            o[j] = (short)f2bf(tile[kv][d]);
        }
        *(short8*)(dst + d * 64 + csp * 8) = o;
    }
}

#define GLD_LDS16(gsrc, ldst) \
    __builtin_amdgcn_global_load_lds((const __attribute__((address_space(1))) uint32_t*)(gsrc), \
                                     (__attribute__((address_space(3))) uint32_t*)(ldst), 16, 0, 0)

// Flash attention fwd. Grid = B * SQ/QBLK = 512 blocks, 256 thr (4 waves).
// K and V^T tiles double-buffered in LDS (16KB each, 64KB total), staged with
// global_load_lds from the pre-swizzled workspace; stage(t+1) overlaps
// compute(t); one __syncthreads per tile (its implicit vmcnt(0) drains DMA).
__global__ __launch_bounds__(256, 2) void fattn(
    const ushort* __restrict__ qb, const ushort* __restrict__ kbt,
    const ushort* __restrict__ vbt, float* __restrict__ out)
{
    __shared__ short8 kls[2][1024];   // [buf][r*16 + chunk] 16KB
    __shared__ short8 vls[2][1024];   // [buf][d*8 + chunk]  16KB

    int bid = blockIdx.x;
    // XCD-bijective swizzle: 512 = 8 XCDs x 64 -> 2 batches' K/V per XCD L2.
    int swz = (bid & 7) * 64 + (bid >> 3);
    int b  = swz >> 5;
    int qt = swz & 31;
    int lane = threadIdx.x & 63;
    int w = threadIdx.x >> 6;
    int g = lane >> 4;
    int qi = lane & 15;
    int rx = qi & 7;
    int qrow = qt * QBLK + w * 16 + qi;

    const ushort* ktile0 = kbt + ((size_t)(b * NT) << 13);
    const ushort* vtile0 = vbt + ((size_t)(b * NT) << 13);

    // Q fragments: lane holds q=qi, d-slots ks*32 + g*8 + j.
    const ushort* qptr = qb + ((size_t)b * SQL + qrow) * DD;
    short8 qf[4];
#pragma unroll
    for (int ks = 0; ks < 4; ++ks)
        qf[ks] = *(const short8*)(qptr + ks * 32 + g * 8);

    f32x4 acc[8];
#pragma unroll
    for (int i = 0; i < 8; ++i) acc[i] = (f32x4)0.f;
    float m = -1e30f, lsum = 0.f;

    // prologue: stage tile 0 into buf 0 (each wave copies its 4KB quarter)
#pragma unroll
    for (int i = 0; i < 4; ++i) {
        int off = w * 4096 + i * 1024;
        GLD_LDS16((const char*)ktile0 + off + lane * 16, (char*)&kls[0][0] + off);
        GLD_LDS16((const char*)vtile0 + off + lane * 16, (char*)&vls[0][0] + off);
    }
    __syncthreads();

    for (int t = 0; t < NT; ++t) {
        int cur = t & 1, nxt = cur ^ 1;
        if (t + 1 < NT) {
            const char* ks = (const char*)ktile0 + ((size_t)(t + 1) << 14);
            const char* vs = (const char*)vtile0 + ((size_t)(t + 1) << 14);
#pragma unroll
            for (int i = 0; i < 4; ++i) {
                int off = w * 4096 + i * 1024;
                GLD_LDS16(ks + off + lane * 16, (char*)&kls[nxt][0] + off);
                GLD_LDS16(vs + off + lane * 16, (char*)&vls[nxt][0] + off);
            }
        }
        // ---- QK^T from LDS: S^T = mfma(K, Q) ----
        f32x4 st[4];
#pragma unroll
        for (int sub = 0; sub < 4; ++sub) {
            f32x4 s = (f32x4)0.f;
            int r = sub * 16 + qi;
#pragma unroll
            for (int ks = 0; ks < 4; ++ks) {
                short8 kf = kls[cur][r * 16 + ((ks * 4 + g) ^ rx)];
                s = __builtin_amdgcn_mfma_f32_16x16x32_bf16(kf, qf[ks], s, 0, 0, 0);
            }
            st[sub] = s;
        }
        // ---- online softmax (scores pre-scaled by 1/sqrt(D)*log2e) ----
        float tmax = st[0][0];
#pragma unroll
        for (int s = 0; s < 4; ++s)
#pragma unroll
            for (int r = 0; r < 4; ++r) tmax = fmaxf(tmax, st[s][r]);
        tmax = fmaxf(tmax, __shfl_xor(tmax, 16));
        tmax = fmaxf(tmax, __shfl_xor(tmax, 32));
        float mnew = fmaxf(m, tmax);
        float alpha = exp2f(m - mnew);
        m = mnew;
        float psum = 0.f;
        short8 pb0, pb1;
#pragma unroll
        for (int s = 0; s < 4; ++s)
#pragma unroll
            for (int r = 0; r < 4; ++r) {
                float p = exp2f(st[s][r] - m);
                psum += p;
                ushort pv = f2bf(p);
                if (s < 2) pb0[s * 4 + r] = (short)pv;
                else       pb1[(s - 2) * 4 + r] = (short)pv;
            }
        lsum = lsum * alpha + psum;
#pragma unroll
        for (int i = 0; i < 8; ++i) {
            acc[i][0] *= alpha; acc[i][1] *= alpha;
            acc[i][2] *= alpha; acc[i][3] *= alpha;
        }
        // ---- PV from LDS: O^T += V^T * P^T ----
#pragma unroll
        for (int dt = 0; dt < 8; ++dt) {
            int d = dt * 16 + qi;
#pragma unroll
            for (int h = 0; h < 2; ++h) {
                short8 vf = vls[cur][d * 8 + ((h * 4 + g) ^ rx)];
                acc[dt] = __builtin_amdgcn_mfma_f32_16x16x32_bf16(vf, h ? pb1 : pb0, acc[dt], 0, 0, 0);
            }
        }
        __syncthreads();   // implicit vmcnt(0)+lgkmcnt(0): stage(t+1) done, reads of cur done
    }

    lsum += __shfl_xor(lsum, 16);
    lsum += __shfl_xor(lsum, 32);
    float inv = 1.f / lsum;
    float* optr = out + ((size_t)b * SQL + qrow) * DD + g * 4;
#pragma unroll
    for (int dt = 0; dt < 8; ++dt) {
        f32x4 o;
        o[0] = acc[dt][0] * inv; o[1] = acc[dt][1] * inv;
        o[2] = acc[dt][2] * inv; o[3] = acc[dt][3] * inv;
        *(f32x4*)(optr + dt * 16) = o;
    }
}

extern "C" void kernel_launch(void* const* d_in, const int* in_sizes, int n_in,
                              void* d_out, int out_size, void* d_ws, size_t ws_size,
                              hipStream_t stream) {
    const float* q = (const float*)d_in[0];
    const float* k = (const float*)d_in[1];
    const float* v = (const float*)d_in[2];
    float* out = (float*)d_out;

    uint8_t* w = (uint8_t*)d_ws;
    size_t tsz = (size_t)NB * SQL * DD * sizeof(ushort);  // 8 MB per tensor
    ushort* qb  = (ushort*)w;
    ushort* kbt = (ushort*)(w + tsz);
    ushort* vbt = (ushort*)(w + 2 * tsz);

    float qscale = 1.4426950408889634f / sqrtf((float)DD);
    int n8 = NB * SQL * DD / 8;
    convert_scale_k<<<n8 / 256, 256, 0, stream>>>(q, qb, qscale);
    convert_k_tiled<<<NB * SKVL * 16 / 256, 256, 0, stream>>>(k, kbt);
    convert_vt_tiled<<<NB * (SKVL / 64), 256, 0, stream>>>(v, vbt);
    fattn<<<NB * (SQL / QBLK), 256, 0, stream>>>(qb, kbt, vbt, out);
}

// Round 6
// 160.328 us; speedup vs baseline: 2.8137x; 1.0334x over previous
//
#include <hip/hip_runtime.h>
#include <hip/hip_bf16.h>
#include <cstdint>
#include <cmath>

#define SQL 2048
#define SKVL 2048
#define DD 128
#define NB 16
#define QBLK 64
#define KVB 64
#define NT (SKVL / KVB)

typedef __attribute__((ext_vector_type(8))) short short8;
typedef __attribute__((ext_vector_type(4))) float f32x4;

__device__ __forceinline__ ushort f2bf(float x) {
    union { float f; uint32_t u; } v; v.f = x;
    uint32_t r = v.u + 0x7FFFu + ((v.u >> 16) & 1u);
    return (ushort)(r >> 16);
}

// fp32 -> bf16 with scale folded in; 8 elements/thread. (Used for Q.)
__global__ void convert_scale_k(const float* __restrict__ in, ushort* __restrict__ out, float scale) {
    size_t i = (size_t)blockIdx.x * blockDim.x + threadIdx.x;
    const f32x4* p = (const f32x4*)in + i * 2;
    f32x4 a = p[0], b = p[1];
    short8 o;
    o[0] = (short)f2bf(a[0] * scale);
    o[1] = (short)f2bf(a[1] * scale);
    o[2] = (short)f2bf(a[2] * scale);
    o[3] = (short)f2bf(a[3] * scale);
    o[4] = (short)f2bf(b[0] * scale);
    o[5] = (short)f2bf(b[1] * scale);
    o[6] = (short)f2bf(b[2] * scale);
    o[7] = (short)f2bf(b[3] * scale);
    *((short8*)out + i) = o;
}

// K fp32 [B][SKV][128] -> tiled swizzled bf16 [B][SKV/64][64 rows x 128 cols].
// Within a 16KB tile: elem (r,c) -> elem index r*128 + ((c>>3)^(r&7))*8 + (c&7).
__global__ void convert_k_tiled(const float* __restrict__ in, ushort* __restrict__ out) {
    int gid = blockIdx.x * blockDim.x + threadIdx.x;   // one 16B out-chunk (8 elems)
    int c16 = gid & 15;
    int rg  = gid >> 4;            // b*SKV + kv
    int r   = rg & 63;
    int tile = rg >> 6;            // b*32 + kt
    const f32x4* p = (const f32x4*)(in + (size_t)rg * DD + c16 * 8);
    f32x4 a = p[0], b = p[1];
    short8 o;
    o[0] = (short)f2bf(a[0]); o[1] = (short)f2bf(a[1]);
    o[2] = (short)f2bf(a[2]); o[3] = (short)f2bf(a[3]);
    o[4] = (short)f2bf(b[0]); o[5] = (short)f2bf(b[1]);
    o[6] = (short)f2bf(b[2]); o[7] = (short)f2bf(b[3]);
    int cs = c16 ^ (r & 7);
    *(short8*)(out + ((size_t)tile << 13) + r * 128 + cs * 8) = o;
}

// V fp32 [B][SKV][128] -> V^T tiled bf16 [B][SKV/64][128 d-rows x 64 kv],
// kv-columns permuted to the PV mfma slot map and XOR-swizzled (see fattn).
__global__ void convert_vt_tiled(const float* __restrict__ v, ushort* __restrict__ vt) {
    __shared__ float tile[64][129];
    int bid = blockIdx.x;          // b*32 + kt
    int kt = bid & 31;
    int b  = bid >> 5;
    int tx = threadIdx.x & 63, ty = threadIdx.x >> 6;  // 64 x 4
    const float* src = v + ((size_t)b * SKVL + (size_t)kt * 64) * DD;
#pragma unroll
    for (int r = ty; r < 64; r += 4) {
        tile[r][tx * 2]     = src[(size_t)r * DD + tx * 2];
        tile[r][tx * 2 + 1] = src[(size_t)r * DD + tx * 2 + 1];
    }
    __syncthreads();
    ushort* dst = vt + ((size_t)bid << 13);
#pragma unroll
    for (int i = 0; i < 4; ++i) {
        int q = threadIdx.x + 256 * i;   // 1024 chunks: d(128) x cs'(8)
        int d = q >> 3;
        int csp = q & 7;
        int cs = csp ^ (d & 7);
        int h = cs >> 2, g = cs & 3;
        short8 o;
#pragma unroll
        for (int j = 0; j < 8; ++j) {
            int kv = h * 32 + g * 4 + (j & 3) + 16 * (j >> 2);
            o[j] = (short)f2bf(tile[kv][d]);
        }
        *(short8*)(dst + d * 64 + csp * 8) = o;
    }
}

#define GLD_LDS16(gsrc, ldst) \
    __builtin_amdgcn_global_load_lds((const __attribute__((address_space(1))) uint32_t*)(gsrc), \
                                     (__attribute__((address_space(3))) uint32_t*)(ldst), 16, 0, 0)

// Flash attention fwd. Grid = B * SQ/QBLK = 512 blocks, 256 thr (4 waves).
// K/V^T double-buffered in LDS (64KB), staged via global_load_lds from the
// pre-swizzled workspace. Defer-max online softmax (THR=11.5 in exp2 domain),
// cvt_pk bf16 P-pack, setprio around MFMA clusters.
__global__ __launch_bounds__(256, 2) void fattn(
    const ushort* __restrict__ qb, const ushort* __restrict__ kbt,
    const ushort* __restrict__ vbt, float* __restrict__ out)
{
    __shared__ short8 kls[2][1024];   // [buf][r*16 + chunk] 16KB
    __shared__ short8 vls[2][1024];   // [buf][d*8 + chunk]  16KB

    int bid = blockIdx.x;
    // XCD-bijective swizzle: 512 = 8 XCDs x 64 -> 2 batches' K/V per XCD L2.
    int swz = (bid & 7) * 64 + (bid >> 3);
    int b  = swz >> 5;
    int qt = swz & 31;
    int lane = threadIdx.x & 63;
    int w = threadIdx.x >> 6;
    int g = lane >> 4;
    int qi = lane & 15;
    int rx = qi & 7;
    int qrow = qt * QBLK + w * 16 + qi;

    const ushort* ktile0 = kbt + ((size_t)(b * NT) << 13);
    const ushort* vtile0 = vbt + ((size_t)(b * NT) << 13);

    // Q fragments: lane holds q=qi, d-slots ks*32 + g*8 + j.
    const ushort* qptr = qb + ((size_t)b * SQL + qrow) * DD;
    short8 qf[4];
#pragma unroll
    for (int ks = 0; ks < 4; ++ks)
        qf[ks] = *(const short8*)(qptr + ks * 32 + g * 8);

    f32x4 acc[8];
#pragma unroll
    for (int i = 0; i < 8; ++i) acc[i] = (f32x4)0.f;
    float m = -1e30f, lsum = 0.f;

    // prologue: stage tile 0 into buf 0 (each wave copies its 4KB quarter)
#pragma unroll
    for (int i = 0; i < 4; ++i) {
        int off = w * 4096 + i * 1024;
        GLD_LDS16((const char*)ktile0 + off + lane * 16, (char*)&kls[0][0] + off);
        GLD_LDS16((const char*)vtile0 + off + lane * 16, (char*)&vls[0][0] + off);
    }
    __syncthreads();

    for (int t = 0; t < NT; ++t) {
        int cur = t & 1, nxt = cur ^ 1;
        if (t + 1 < NT) {
            const char* ks = (const char*)ktile0 + ((size_t)(t + 1) << 14);
            const char* vs = (const char*)vtile0 + ((size_t)(t + 1) << 14);
#pragma unroll
            for (int i = 0; i < 4; ++i) {
                int off = w * 4096 + i * 1024;
                GLD_LDS16(ks + off + lane * 16, (char*)&kls[nxt][0] + off);
                GLD_LDS16(vs + off + lane * 16, (char*)&vls[nxt][0] + off);
            }
        }
        // ---- QK^T from LDS: S^T = mfma(K, Q) ----
        f32x4 st[4];
        __builtin_amdgcn_s_setprio(1);
#pragma unroll
        for (int sub = 0; sub < 4; ++sub) {
            f32x4 s = (f32x4)0.f;
            int r = sub * 16 + qi;
#pragma unroll
            for (int ks = 0; ks < 4; ++ks) {
                short8 kf = kls[cur][r * 16 + ((ks * 4 + g) ^ rx)];
                s = __builtin_amdgcn_mfma_f32_16x16x32_bf16(kf, qf[ks], s, 0, 0, 0);
            }
            st[sub] = s;
        }
        __builtin_amdgcn_s_setprio(0);
        // ---- online softmax, defer-max (scores pre-scaled by log2e/sqrt(D)) ----
        float m0 = fmaxf(fmaxf(st[0][0], st[0][1]), fmaxf(st[0][2], st[0][3]));
        float m1 = fmaxf(fmaxf(st[1][0], st[1][1]), fmaxf(st[1][2], st[1][3]));
        float m2 = fmaxf(fmaxf(st[2][0], st[2][1]), fmaxf(st[2][2], st[2][3]));
        float m3 = fmaxf(fmaxf(st[3][0], st[3][1]), fmaxf(st[3][2], st[3][3]));
        float tmax = fmaxf(fmaxf(m0, m1), fmaxf(m2, m3));
        tmax = fmaxf(tmax, __shfl_xor(tmax, 16));
        tmax = fmaxf(tmax, __shfl_xor(tmax, 32));
        if (!__all(tmax - m <= 11.5f)) {   // rescale only when max grows a lot
            float mnew = fmaxf(m, tmax);
            float alpha = exp2f(m - mnew);
            m = mnew;
            lsum *= alpha;
#pragma unroll
            for (int i = 0; i < 8; ++i) {
                acc[i][0] *= alpha; acc[i][1] *= alpha;
                acc[i][2] *= alpha; acc[i][3] *= alpha;
            }
        }
        float pv[16];
        float ps[4];
#pragma unroll
        for (int s = 0; s < 4; ++s) {
            pv[s * 4 + 0] = exp2f(st[s][0] - m);
            pv[s * 4 + 1] = exp2f(st[s][1] - m);
            pv[s * 4 + 2] = exp2f(st[s][2] - m);
            pv[s * 4 + 3] = exp2f(st[s][3] - m);
            ps[s] = (pv[s * 4 + 0] + pv[s * 4 + 1]) + (pv[s * 4 + 2] + pv[s * 4 + 3]);
        }
        lsum += (ps[0] + ps[1]) + (ps[2] + ps[3]);
        union { short8 v; uint32_t u[4]; } P0, P1;
#pragma unroll
        for (int i = 0; i < 4; ++i) {
            asm("v_cvt_pk_bf16_f32 %0, %1, %2" : "=v"(P0.u[i]) : "v"(pv[2 * i]), "v"(pv[2 * i + 1]));
            asm("v_cvt_pk_bf16_f32 %0, %1, %2" : "=v"(P1.u[i]) : "v"(pv[8 + 2 * i]), "v"(pv[8 + 2 * i + 1]));
        }
        // ---- PV from LDS: O^T += V^T * P^T ----
        __builtin_amdgcn_s_setprio(1);
#pragma unroll
        for (int dt = 0; dt < 8; ++dt) {
            int d = dt * 16 + qi;
            acc[dt] = __builtin_amdgcn_mfma_f32_16x16x32_bf16(
                vls[cur][d * 8 + (g ^ rx)], P0.v, acc[dt], 0, 0, 0);
            acc[dt] = __builtin_amdgcn_mfma_f32_16x16x32_bf16(
                vls[cur][d * 8 + ((4 + g) ^ rx)], P1.v, acc[dt], 0, 0, 0);
        }
        __builtin_amdgcn_s_setprio(0);
        __syncthreads();   // stage(t+1) done (vmcnt0), reads of cur done
    }

    lsum += __shfl_xor(lsum, 16);
    lsum += __shfl_xor(lsum, 32);
    float inv = 1.f / lsum;
    float* optr = out + ((size_t)b * SQL + qrow) * DD + g * 4;
#pragma unroll
    for (int dt = 0; dt < 8; ++dt) {
        f32x4 o;
        o[0] = acc[dt][0] * inv; o[1] = acc[dt][1] * inv;
        o[2] = acc[dt][2] * inv; o[3] = acc[dt][3] * inv;
        *(f32x4*)(optr + dt * 16) = o;
    }
}

extern "C" void kernel_launch(void* const* d_in, const int* in_sizes, int n_in,
                              void* d_out, int out_size, void* d_ws, size_t ws_size,
                              hipStream_t stream) {
    const float* q = (const float*)d_in[0];
    const float* k = (const float*)d_in[1];
    const float* v = (const float*)d_in[2];
    float* out = (float*)d_out;

    uint8_t* w = (uint8_t*)d_ws;
    size_t tsz = (size_t)NB * SQL * DD * sizeof(ushort);  // 8 MB per tensor
    ushort* qb  = (ushort*)w;
    ushort* kbt = (ushort*)(w + tsz);
    ushort* vbt = (ushort*)(w + 2 * tsz);

    float qscale = 1.4426950408889634f / sqrtf((float)DD);
    int n8 = NB * SQL * DD / 8;
    convert_scale_k<<<n8 / 256, 256, 0, stream>>>(q, qb, qscale);
    convert_k_tiled<<<NB * SKVL * 16 / 256, 256, 0, stream>>>(k, kbt);
    convert_vt_tiled<<<NB * (SKVL / 64), 256, 0, stream>>>(v, vbt);
    fattn<<<NB * (SQL / QBLK), 256, 0, stream>>>(qb, kbt, vbt, out);
}